// Round 12
// baseline (122.898 us; speedup 1.0000x reference)
//
#include <hip/hip_runtime.h>
#include <stdint.h>

// q,k,v: [B=8, d=768, N=6144] fp32; head_dim=32, kernel_size=3
// h=24 heads, g=2048 windows; window elem j of window gg at n = j*2048 + gg
// out flat: [b][gg][hh][kq][dd] contiguous [8, 2048, 24, 3, 32]
//
// Round 12: final width-axis probe. r8->r11 (64B->128B read islands) gave
// +9% service rate with everything else flat. This doubles once more:
// 4 windows/thread, float4 loads -> 256B contiguous islands per 16-lane
// slice group. Skeleton unchanged (proven floors: FETCH 221MB, WRITE 151MB):
//  - 4 threads/window-quad: lane = slice*16 + wl; slice owns dd-octet.
//  - partial scores (float4 across 4 windows) combined via shfl_xor(16/32);
//    softmax redundant per slice, fully static indexing (no scratch).
//  - v preloaded (24 float4 = 96 regs) before shuffle+softmax VALU phase.
//  - stores: per (win,kq) 32B piece at slice*8; 4 slices complete each 64B
//    line cross-lane (measured amp-free in r8/r11).
//  - ~160 VGPR -> 3 waves/SIMD (12/CU): proven non-binding (r4-r9).
constexpr int CB = 8;
constexpr int CD = 768;
constexpr int CN = 6144;
constexpr int HD = 32;
constexpr int KS = 3;
constexpr int CH = CD / HD;        // 24
constexpr int CG = CN / KS;        // 2048
constexpr int OSTR = CH * KS * HD; // 2304

__device__ __forceinline__ float c4(const float4& f, int w) {
  switch (w) { case 0: return f.x; case 1: return f.y; case 2: return f.z; default: return f.w; }
}

__global__ __launch_bounds__(256) void dilate_attn_kernel(
    const float* __restrict__ q, const float* __restrict__ k,
    const float* __restrict__ v, float* __restrict__ out) {
  const int tid   = blockIdx.x * 256 + threadIdx.x;
  const int lane  = threadIdx.x & 63;
  const int wav   = tid >> 6;              // 0..6143
  const int slice = lane >> 4;             // dd-octet owner
  const int wl    = lane & 15;             // quad within wave
  const int wq    = (wav & 31) * 16 + wl;  // window-quad 0..511
  const int bh    = wav >> 5;              // b*24 + hh
  const int hh    = bh % CH;
  const int b     = bh / CH;
  const int gg    = wq * 4;                // windows gg..gg+3

  // element offset of (row dd = hh*32+slice*8, j=0, col gg); 16B-aligned
  const uint32_t inoff = (uint32_t)(b * CD + hh * HD + slice * 8) * (uint32_t)CN
                       + (uint32_t)gg;

  // ---- partial scores over this slice's 8 dd; [kq][kj][win]
  float s[3][3][4];
  #pragma unroll
  for (int a = 0; a < 3; ++a)
    #pragma unroll
    for (int c = 0; c < 3; ++c)
      #pragma unroll
      for (int w = 0; w < 4; ++w) s[a][c][w] = 0.f;

  #pragma unroll
  for (int d = 0; d < 8; ++d) {
    const uint32_t o = inoff + (uint32_t)d * CN;
    const float4 q0 = *reinterpret_cast<const float4*>(q + o);
    const float4 q1 = *reinterpret_cast<const float4*>(q + o + CG);
    const float4 q2 = *reinterpret_cast<const float4*>(q + o + 2 * CG);
    const float4 k0 = *reinterpret_cast<const float4*>(k + o);
    const float4 k1 = *reinterpret_cast<const float4*>(k + o + CG);
    const float4 k2 = *reinterpret_cast<const float4*>(k + o + 2 * CG);
    #pragma unroll
    for (int w = 0; w < 4; ++w) {
      const float a0 = c4(q0, w), a1 = c4(q1, w), a2 = c4(q2, w);
      const float b0 = c4(k0, w), b1 = c4(k1, w), b2 = c4(k2, w);
      s[0][0][w] = fmaf(a0, b0, s[0][0][w]);
      s[0][1][w] = fmaf(a0, b1, s[0][1][w]);
      s[0][2][w] = fmaf(a0, b2, s[0][2][w]);
      s[1][0][w] = fmaf(a1, b0, s[1][0][w]);
      s[1][1][w] = fmaf(a1, b1, s[1][1][w]);
      s[1][2][w] = fmaf(a1, b2, s[1][2][w]);
      s[2][0][w] = fmaf(a2, b0, s[2][0][w]);
      s[2][1][w] = fmaf(a2, b1, s[2][1][w]);
      s[2][2][w] = fmaf(a2, b2, s[2][2][w]);
    }
  }

  // ---- issue v loads now; latency hides under shuffles + softmax
  float vv[3][8][4];
  #pragma unroll
  for (int d = 0; d < 8; ++d) {
    const uint32_t o = inoff + (uint32_t)d * CN;
    const float4 v0 = *reinterpret_cast<const float4*>(v + o);
    const float4 v1 = *reinterpret_cast<const float4*>(v + o + CG);
    const float4 v2 = *reinterpret_cast<const float4*>(v + o + 2 * CG);
    #pragma unroll
    for (int w = 0; w < 4; ++w) {
      vv[0][d][w] = c4(v0, w); vv[1][d][w] = c4(v1, w); vv[2][d][w] = c4(v2, w);
    }
  }

  // ---- combine partial scores across the 4 slices (lane^16, lane^32)
  #pragma unroll
  for (int a = 0; a < 3; ++a)
    #pragma unroll
    for (int c = 0; c < 3; ++c)
      #pragma unroll
      for (int w = 0; w < 4; ++w) s[a][c][w] += __shfl_xor(s[a][c][w], 16);
  #pragma unroll
  for (int a = 0; a < 3; ++a)
    #pragma unroll
    for (int c = 0; c < 3; ++c)
      #pragma unroll
      for (int w = 0; w < 4; ++w) s[a][c][w] += __shfl_xor(s[a][c][w], 32);

  // ---- softmax over kj, in place, per (window, kq); redundant per slice
  const float scale = 0.17677669529663687f;  // 32^-0.5
  #pragma unroll
  for (int w = 0; w < 4; ++w) {
    #pragma unroll
    for (int a = 0; a < 3; ++a) {
      const float x0 = s[a][0][w] * scale;
      const float x1 = s[a][1][w] * scale;
      const float x2 = s[a][2][w] * scale;
      const float m  = fmaxf(fmaxf(x0, x1), x2);
      const float e0 = __expf(x0 - m), e1 = __expf(x1 - m), e2 = __expf(x2 - m);
      const float r  = 1.f / (e0 + e1 + e2);
      s[a][0][w] = e0 * r; s[a][1][w] = e1 * r; s[a][2][w] = e2 * r;
    }
  }

  // ---- PV from registers + stores: per (win,kq) one 32B piece at slice*8;
  // 4 slices (lanes 16 apart) complete each 64B line (measured amp-free)
  const uint32_t ooff = (uint32_t)(b * CG + gg) * (uint32_t)OSTR
                      + (uint32_t)(hh * KS * HD + slice * 8);
  #pragma unroll
  for (int w = 0; w < 4; ++w) {
    const uint32_t ow = ooff + (uint32_t)w * OSTR;
    #pragma unroll
    for (int a = 0; a < 3; ++a) {
      float o_[8];
      #pragma unroll
      for (int d = 0; d < 8; ++d)
        o_[d] = fmaf(s[a][0][w], vv[0][d][w],
                fmaf(s[a][1][w], vv[1][d][w], s[a][2][w] * vv[2][d][w]));
      *reinterpret_cast<float4*>(out + ow + a * HD)     = make_float4(o_[0], o_[1], o_[2], o_[3]);
      *reinterpret_cast<float4*>(out + ow + a * HD + 4) = make_float4(o_[4], o_[5], o_[6], o_[7]);
    }
  }
}

extern "C" void kernel_launch(void* const* d_in, const int* in_sizes, int n_in,
                              void* d_out, int out_size, void* d_ws, size_t ws_size,
                              hipStream_t stream) {
  const float* q = (const float*)d_in[0];
  const float* k = (const float*)d_in[1];
  const float* v = (const float*)d_in[2];
  float* out = (float*)d_out;

  // 8*24*512 quads * 4 threads = 393216 threads -> 1536 blocks (6144 waves)
  const int total = CB * CH * (CG / 4) * 4;
  const int blocks = total / 256;
  dilate_attn_kernel<<<blocks, 256, 0, stream>>>(q, k, v, out);
}